// Round 7
// baseline (300.860 us; speedup 1.0000x reference)
//
#include <hip/hip_runtime.h>

typedef __bf16 bf16;
typedef __bf16 bf16x8 __attribute__((ext_vector_type(8)));
typedef float  f32x4  __attribute__((ext_vector_type(4)));

#define MFMA(a, b, c) __builtin_amdgcn_mfma_f32_16x16x32_bf16((a), (b), (c), 0, 0, 0)

static constexpr int B_   = 2;
static constexpr int T_   = 2048;
static constexpr int D_   = 1024;
static constexpr int NH_  = 16;
static constexpr int HD_  = 64;
static constexpr int WIN_ = 256;
static constexpr int M_   = B_ * T_;          // 4096
static constexpr int NQKV = D_ + 2 * HD_;     // 1152

// ATTRIBUTION PROBE ROUND: each compute kernel repeats its work REPS times
// (bit-identical, idempotent) so per-kernel duration exceeds the 44µs harness
// fill floor and surfaces in rocprof top-5 with real counters. attn made
// out-of-place (writes ob, q stays pristine) so reps are idempotent.
// Unit time = dur_us(row)/REPS. REPS returns to 1 next round.
static constexpr int REPS_G1 = 5;
static constexpr int REPS_AT = 4;
static constexpr int REPS_G2 = 5;

// softmax scale 1/sqrt(64) with log2(e) folded in: attention uses exp2
static constexpr float QSCALE = 0.125f * 1.44269504088896f;

// async global->LDS, 16B per lane; global addr per-lane, LDS dst wave-uniform
__device__ __forceinline__ void gld_lds16(const bf16* g, bf16* l) {
  __builtin_amdgcn_global_load_lds(
      (const __attribute__((address_space(1))) void*)g,
      (__attribute__((address_space(3))) void*)l, 16, 0, 0);
}

// ---------------------------------------------------------------------------
// BANK-CONFLICT SWIZZLE (rule #21, m201/m173 pattern; VERIFIED −12.6µs in R5).
//   write: lane stages global col ((lane&7)^(lane>>3))*8   (row&7 == lane>>3)
//   read : col' = col ^ ((row&7)*8)                        (row&7 == l16&7)
// ---------------------------------------------------------------------------

// ---------------------------------------------------------------------------
// Fused fp32->bf16 conversion of all 6 inputs. Wq/Wk/Wv -> Wqkv[1152][1024].
// ---------------------------------------------------------------------------
__global__ __launch_bounds__(256) void conv_all(
    const float* __restrict__ x,  const float* __restrict__ wq,
    const float* __restrict__ wk, const float* __restrict__ wv,
    const float* __restrict__ wf, const float* __restrict__ bv,
    bf16* __restrict__ xc, bf16* __restrict__ wqkv,
    bf16* __restrict__ wfc, bf16* __restrict__ bfc) {
  const long i = (long)(blockIdx.x * 256 + threadIdx.x) * 4;
  const float* src; bf16* dst; long off;
  if      (i < 4194304L) { src = x;  dst = xc;              off = 0; }
  else if (i < 5242880L) { src = wq; dst = wqkv;            off = 4194304L; }
  else if (i < 5308416L) { src = wk; dst = wqkv + 1048576L; off = 5242880L; }
  else if (i < 5373952L) { src = wv; dst = wqkv + 1114112L; off = 5308416L; }
  else if (i < 6422528L) { src = wf; dst = wfc;             off = 5373952L; }
  else if (i < 6423552L) { src = bv; dst = bfc;             off = 6422528L; }
  else return;
  const long j = i - off;
  const float4 v = *(const float4*)(src + j);
  bf16 o[4] = {(bf16)v.x, (bf16)v.y, (bf16)v.z, (bf16)v.w};
  *(uint2*)(dst + j) = *(const uint2*)o;
}

// ---------------------------------------------------------------------------
// GEMM, tile M=64 x N=128, BK=64, dbuf + swizzle, 4 waves (R6 structure).
// REPS: outer repeat of the full K-loop + epilogue (identical result).
// C[M,N] = A[M,K] @ B[N,K]^T.
// EPI=1: QKV split (q scaled by QSCALE / k / vT transposed). EPI=2: fp32+bias.
// ---------------------------------------------------------------------------
template <int EPI, int REPS>
__global__ __launch_bounds__(256) void gemm64x128(
    const bf16* __restrict__ A, const bf16* __restrict__ Bw,
    void* __restrict__ Cout, const bf16* __restrict__ bias,
    bf16* __restrict__ kb, bf16* __restrict__ vT, int N, int K) {
  __shared__ __align__(16) bf16 As[2][64 * 64];    // 2 x  8 KB
  __shared__ __align__(16) bf16 Bs[2][128 * 64];   // 2 x 16 KB

  const int tid  = threadIdx.x;
  const int w    = tid >> 6;
  const int lane = tid & 63;
  const int quad = lane >> 4;
  const int l16  = lane & 15;
  const int wm   = w & 1;   // row half (32 rows)
  const int wn   = w >> 1;  // col half (64 cols)
  const int m0   = blockIdx.x * 64;
  const int n0   = blockIdx.y * 128;
  const int lrow = lane >> 3;                   // 0..7 (== row&7 staged)
  const int scol = ((lane & 7) ^ lrow) * 8;     // pre-swizzled source col
  const int rx   = (l16 & 7) * 8;               // read-side XOR term

  auto stage = [&](int buf, int k0) {
#pragma unroll
    for (int t = 0; t < 6; ++t) {
      const int inst = w * 6 + t;  // wave-uniform
      if (inst < 8) {
        gld_lds16(&A[(size_t)(m0 + inst * 8 + lrow) * K + k0 + scol],
                  &As[buf][inst * 512]);
      } else {
        const int bi = inst - 8;
        gld_lds16(&Bw[(size_t)(n0 + bi * 8 + lrow) * K + k0 + scol],
                  &Bs[buf][bi * 512]);
      }
    }
  };

  for (int rep = 0; rep < REPS; ++rep) {
    f32x4 acc[2][4] = {};

    auto compute = [&](int buf) {
#pragma unroll
      for (int kk = 0; kk < 64; kk += 32) {
        const int c = (kk + quad * 8) ^ rx;  // swizzled column
        bf16x8 a[2], b[4];
#pragma unroll
        for (int i = 0; i < 2; ++i)
          a[i] = *(const bf16x8*)&As[buf][(wm * 32 + i * 16 + l16) * 64 + c];
#pragma unroll
        for (int j = 0; j < 4; ++j)
          b[j] = *(const bf16x8*)&Bs[buf][(wn * 64 + j * 16 + l16) * 64 + c];
#pragma unroll
        for (int i = 0; i < 2; ++i)
#pragma unroll
          for (int j = 0; j < 4; ++j) acc[i][j] = MFMA(a[i], b[j], acc[i][j]);
      }
    };

    stage(0, 0);
    __syncthreads();   // all waves past prior rep's reads; buf0 staged
    int cur = 0;
    for (int k0 = 64; k0 < K; k0 += 64) {
      stage(cur ^ 1, k0);
      compute(cur);
      __syncthreads();
      cur ^= 1;
    }
    compute(cur);

    // epilogue: C/D layout col=l16, row=quad*4+r (m89-verified)
#pragma unroll
    for (int i = 0; i < 2; ++i) {
#pragma unroll
      for (int j = 0; j < 4; ++j) {
        const int col     = n0 + wn * 64 + j * 16 + l16;
        const int rowbase = m0 + wm * 32 + i * 16 + quad * 4;
        if (EPI == 1) {
          if (col < D_) {
            bf16* qb = (bf16*)Cout;
#pragma unroll
            for (int r = 0; r < 4; ++r)
              qb[(size_t)(rowbase + r) * D_ + col] = (bf16)(acc[i][j][r] * QSCALE);
          } else if (col < D_ + HD_) {
#pragma unroll
            for (int r = 0; r < 4; ++r)
              kb[(size_t)(rowbase + r) * HD_ + (col - D_)] = (bf16)acc[i][j][r];
          } else {
            bf16 o[4] = {(bf16)acc[i][j][0], (bf16)acc[i][j][1],
                         (bf16)acc[i][j][2], (bf16)acc[i][j][3]};
            *(uint2*)&vT[(size_t)(col - D_ - HD_) * M_ + rowbase] = *(const uint2*)o;
          }
        } else {
          float* outp = (float*)Cout;
          const float bvv = (float)bias[col];
#pragma unroll
          for (int r = 0; r < 4; ++r)
            outp[(size_t)(rowbase + r) * D_ + col] = acc[i][j][r] + bvv;
        }
      }
    }
  }
}

// ---------------------------------------------------------------------------
// Windowed attention (MQA), R6 structure (1 barrier/s-step, wave-private Ps,
// Q-hoist, swizzled Ks/Vt). NOW OUT-OF-PLACE: writes o != q, so REPS repeats
// are idempotent (q pristine; each rep recomputes identical o).
// ---------------------------------------------------------------------------
template <int REPS>
__global__ __launch_bounds__(256) void attn_win128(
    const bf16* __restrict__ q, const bf16* __restrict__ k,
    const bf16* __restrict__ vT, bf16* __restrict__ o) {
  __shared__ __align__(16) bf16 Ks[2][64 * 64];   // 16 KB
  __shared__ __align__(16) bf16 Vt[2][64 * 64];   // 16 KB [h][s]
  __shared__ __align__(16) bf16 Ps[128 * 72];     // 18 KB padded (wave-private)
  __shared__ float ls[4][32];

  const int tid  = threadIdx.x;
  const int w    = tid >> 6;
  const int lane = tid & 63;
  const int quad = lane >> 4;
  const int l16  = lane & 15;
  const int lrow = lane >> 3;
  const int scol = ((lane & 7) ^ lrow) * 8;
  const int rx   = (l16 & 7) * 8;

  const int t0 = blockIdx.x * 128;
  const int n  = blockIdx.y;
  const int b  = blockIdx.z;

  auto stageKV = [&](int st, int pb) {
#pragma unroll
    for (int t = 0; t < 2; ++t) {
      const int inst = w * 2 + t;
      gld_lds16(&k[((size_t)(b * T_ + st + inst * 8 + lrow)) * HD_ + scol],
                &Ks[pb][inst * 512]);
      gld_lds16(&vT[(size_t)(inst * 8 + lrow) * M_ + b * T_ + st + scol],
                &Vt[pb][inst * 512]);
    }
  };

  const int st_lo = (t0 - WIN_ > 0) ? t0 - WIN_ : 0;
  const int st_hi = (t0 + WIN_ + 64 < T_ - 64) ? t0 + WIN_ + 64 : T_ - 64;

  // Q-hoist: wave's B-fragments for both kk slices (q never overwritten now)
  bf16x8 qf[2][2];
#pragma unroll
  for (int tt = 0; tt < 2; ++tt)
#pragma unroll
    for (int kq = 0; kq < 2; ++kq)
      qf[tt][kq] = *(const bf16x8*)
          &q[((size_t)(b * T_ + t0 + w * 32 + tt * 16 + l16)) * D_ +
             n * HD_ + kq * 32 + quad * 8];

  for (int rep = 0; rep < REPS; ++rep) {
    stageKV(st_lo, 0);
    int pb = 0;

    f32x4 o_acc[2][4] = {};
    float l_part[2] = {0.0f, 0.0f};

    for (int st = st_lo; st <= st_hi; st += 64) {
      __syncthreads();  // drains vmcnt: buf[pb] ready; prior reads done
      if (st + 64 <= st_hi) stageKV(st + 64, pb ^ 1);

      // S^T = K Q^T
      f32x4 sacc[4][2] = {};
#pragma unroll
      for (int kk = 0; kk < 64; kk += 32) {
        const int c = (kk + quad * 8) ^ rx;
        bf16x8 ak[4];
#pragma unroll
        for (int stile = 0; stile < 4; ++stile)
          ak[stile] = *(const bf16x8*)&Ks[pb][(stile * 16 + l16) * 64 + c];
        __builtin_amdgcn_s_setprio(1);
#pragma unroll
        for (int stile = 0; stile < 4; ++stile)
#pragma unroll
          for (int tt = 0; tt < 2; ++tt)
            sacc[stile][tt] = MFMA(ak[stile], qf[tt][kk >> 5], sacc[stile][tt]);
        __builtin_amdgcn_s_setprio(0);
      }

      // softmax numerators (exp2) -> Ps (wave-private rows)
      const int off_t = st - t0;
      const bool need_mask =
          (off_t < w * 32 - (WIN_ - 31)) || (off_t > w * 32 + (WIN_ - 63));
      if (!need_mask) {
#pragma unroll
        for (int tt = 0; tt < 2; ++tt) {
#pragma unroll
          for (int stile = 0; stile < 4; ++stile) {
            bf16 pk[4];
            float psum = 0.0f;
#pragma unroll
            for (int r = 0; r < 4; ++r) {
              const float p =
                  __builtin_amdgcn_exp2f(fminf(sacc[stile][tt][r], 43.28f));
              psum += p;
              pk[r] = (bf16)p;
            }
            l_part[tt] += psum;
            *(uint2*)&Ps[(w * 32 + tt * 16 + l16) * 72 + stile * 16 + quad * 4] =
                *(const uint2*)pk;
          }
        }
      } else {
#pragma unroll
        for (int tt = 0; tt < 2; ++tt) {
          const int t = t0 + w * 32 + tt * 16 + l16;
#pragma unroll
          for (int stile = 0; stile < 4; ++stile) {
            bf16 pk[4];
            float psum = 0.0f;
#pragma unroll
            for (int r = 0; r < 4; ++r) {
              const int s = st + stile * 16 + quad * 4 + r;
              const int d = t - s;
              const float p =
                  (d > WIN_ || d < -WIN_)
                      ? 0.0f
                      : __builtin_amdgcn_exp2f(fminf(sacc[stile][tt][r], 43.28f));
              psum += p;
              pk[r] = (bf16)p;
            }
            l_part[tt] += psum;
            *(uint2*)&Ps[(w * 32 + tt * 16 + l16) * 72 + stile * 16 + quad * 4] =
                *(const uint2*)pk;
          }
        }
      }
      // no barrier: Ps rows wave-private; lgkmcnt orders write->read.

      // O += P V
#pragma unroll
      for (int kk = 0; kk < 64; kk += 32) {
        const int c = (kk + quad * 8) ^ rx;
        bf16x8 ap[2];
#pragma unroll
        for (int rg = 0; rg < 2; ++rg)
          ap[rg] = *(const bf16x8*)&Ps[(w * 32 + rg * 16 + l16) * 72 + kk + quad * 8];
        __builtin_amdgcn_s_setprio(1);
#pragma unroll
        for (int nt = 0; nt < 4; ++nt) {
          bf16x8 bv = *(const bf16x8*)&Vt[pb][(nt * 16 + l16) * 64 + c];
#pragma unroll
          for (int rg = 0; rg < 2; ++rg)
            o_acc[rg][nt] = MFMA(ap[rg], bv, o_acc[rg][nt]);
        }
        __builtin_amdgcn_s_setprio(0);
      }
      pb ^= 1;
    }

    // finalize l[t]: quad-reduce, redistribute via ls
#pragma unroll
    for (int tt = 0; tt < 2; ++tt) {
      l_part[tt] += __shfl_xor(l_part[tt], 16);
      l_part[tt] += __shfl_xor(l_part[tt], 32);
      if (quad == 0) ls[w][tt * 16 + l16] = l_part[tt];
    }
    __syncthreads();

#pragma unroll
    for (int rg = 0; rg < 2; ++rg) {
#pragma unroll
      for (int r = 0; r < 4; ++r) {
        const float lr = ls[w][rg * 16 + quad * 4 + r] + 1e-30f;
        const int t = t0 + w * 32 + rg * 16 + quad * 4 + r;
#pragma unroll
        for (int nt = 0; nt < 4; ++nt) {
          const int h = nt * 16 + l16;
          o[((size_t)(b * T_ + t)) * D_ + n * HD_ + h] =
              (bf16)(o_acc[rg][nt][r] / lr);
        }
      }
    }
    __syncthreads();  // ls safe for next rep
  }
}

// ---------------------------------------------------------------------------
extern "C" void kernel_launch(void* const* d_in, const int* in_sizes, int n_in,
                              void* d_out, int out_size, void* d_ws, size_t ws_size,
                              hipStream_t stream) {
  float* out = (float*)d_out;  // reference output dtype is float32

  bf16* xc   = (bf16*)d_ws;                   // 4096 x 1024
  bf16* wqkv = xc   + (size_t)M_ * D_;        // 1152 x 1024
  bf16* wfc  = wqkv + (size_t)NQKV * D_;      // 1024 x 1024
  bf16* bfc  = wfc  + (size_t)D_ * D_;        // 1024
  bf16* qb   = bfc  + D_;                     // 4096 x 1024
  bf16* kb   = qb   + (size_t)M_ * D_;        // 4096 x 64
  bf16* vT   = kb   + (size_t)M_ * HD_;       // 64 x 4096 (transposed)
  bf16* ob   = vT   + (size_t)HD_ * M_;       // 4096 x 1024 (attn out, sep.)

  dim3 blk(256);
  conv_all<<<dim3((6423552 / 4 + 255) / 256), blk, 0, stream>>>(
      (const float*)d_in[0], (const float*)d_in[1], (const float*)d_in[2],
      (const float*)d_in[3], (const float*)d_in[4], (const float*)d_in[5],
      xc, wqkv, wfc, bfc);

  gemm64x128<1, REPS_G1><<<dim3(M_ / 64, NQKV / 128), blk, 0, stream>>>(
      xc, wqkv, (void*)qb, nullptr, kb, vT, NQKV, D_);

  attn_win128<REPS_AT><<<dim3(T_ / 128, NH_, B_), blk, 0, stream>>>(
      qb, kb, vT, ob);

  gemm64x128<2, REPS_G2><<<dim3(M_ / 64, D_ / 128), blk, 0, stream>>>(
      ob, wfc, (void*)out, bfc, nullptr, nullptr, D_, D_);
}

// Round 12
// 138.856 us; speedup vs baseline: 2.1667x; 2.1667x over previous
//
#include <hip/hip_runtime.h>

typedef __bf16 bf16;
typedef __bf16 bf16x8 __attribute__((ext_vector_type(8)));
typedef float  f32x4  __attribute__((ext_vector_type(4)));

#define MFMA(a, b, c) __builtin_amdgcn_mfma_f32_16x16x32_bf16((a), (b), (c), 0, 0, 0)

static constexpr int B_   = 2;
static constexpr int T_   = 2048;
static constexpr int D_   = 1024;
static constexpr int NH_  = 16;
static constexpr int HD_  = 64;
static constexpr int WIN_ = 256;
static constexpr int M_   = B_ * T_;          // 4096
static constexpr int NQKV = D_ + 2 * HD_;     // 1152

// softmax scale 1/sqrt(64) with log2(e) folded in: attention uses exp2
static constexpr float QSCALE = 0.125f * 1.44269504088896f;

// async global->LDS, 16B per lane; global addr per-lane, LDS dst wave-uniform
__device__ __forceinline__ void gld_lds16(const bf16* g, bf16* l) {
  __builtin_amdgcn_global_load_lds(
      (const __attribute__((address_space(1))) void*)g,
      (__attribute__((address_space(3))) void*)l, 16, 0, 0);
}

// ---------------------------------------------------------------------------
// BANK-CONFLICT SWIZZLE (rule #21, m201/m173 pattern; VERIFIED −12.6µs in R5).
// Staged tiles are [R][64] bf16 (128 B rows = exact bank wrap): un-swizzled,
// a quad's 16 lanes land on the same 4 banks (16-way). Fix: LDS stays linear
// (gld_lds16 requirement); global SOURCE column pre-swizzled per-lane, same
// XOR on every read:
//   write: lane stages global col ((lane&7)^(lane>>3))*8   (row&7 == lane>>3)
//   read : col' = col ^ ((row&7)*8)                        (row&7 == l16&7)
// Post-swizzle: quad spans all 32 banks (2-way residual = free, m136).
//
// NOTE (R8-R10 lesson): single-kernel fusion with a software grid barrier
// fails with fence-strength-INDEPENDENT patchy errors (agent fence == system
// seq_cst fence, absmax ~0.25 both) — mechanism unresolved; do not retry
// without disasm of the failing binary. Multi-kernel is the verified path.
// (R11 was a container-infrastructure failure — this source was never run.)
// ---------------------------------------------------------------------------

// ---------------------------------------------------------------------------
// Fused fp32->bf16 conversion of all 6 inputs. Wq/Wk/Wv -> Wqkv[1152][1024].
// (Folding conversions into GEMM staging was evaluated and REJECTED: the
// reused operands are re-read 9x/32x, so f32 staging doubles 144MB of
// LLC-class traffic — gemm1 sits at that roofline already.)
// ---------------------------------------------------------------------------
__global__ __launch_bounds__(256) void conv_all(
    const float* __restrict__ x,  const float* __restrict__ wq,
    const float* __restrict__ wk, const float* __restrict__ wv,
    const float* __restrict__ wf, const float* __restrict__ bv,
    bf16* __restrict__ xc, bf16* __restrict__ wqkv,
    bf16* __restrict__ wfc, bf16* __restrict__ bfc) {
  const long i = (long)(blockIdx.x * 256 + threadIdx.x) * 4;
  const float* src; bf16* dst; long off;
  if      (i < 4194304L) { src = x;  dst = xc;              off = 0; }
  else if (i < 5242880L) { src = wq; dst = wqkv;            off = 4194304L; }
  else if (i < 5308416L) { src = wk; dst = wqkv + 1048576L; off = 5242880L; }
  else if (i < 5373952L) { src = wv; dst = wqkv + 1114112L; off = 5308416L; }
  else if (i < 6422528L) { src = wf; dst = wfc;             off = 5373952L; }
  else if (i < 6423552L) { src = bv; dst = bfc;             off = 6422528L; }
  else return;
  const long j = i - off;
  const float4 v = *(const float4*)(src + j);
  bf16 o[4] = {(bf16)v.x, (bf16)v.y, (bf16)v.z, (bf16)v.w};
  *(uint2*)(dst + j) = *(const uint2*)o;
}

// ---------------------------------------------------------------------------
// GEMM, tile 128x128, BK=64, 2-phase double-buffer, 4 waves + XOR swizzle
// (R5 config — best measured across 5 structural variants R0-R6).
// C[M,N] = A[M,K] @ B[N,K]^T.
// EPI=1: QKV split (q scaled by QSCALE / k / vT transposed). EPI=2: fp32+bias.
// ---------------------------------------------------------------------------
template <int EPI>
__global__ __launch_bounds__(256) void gemm128x128(
    const bf16* __restrict__ A, const bf16* __restrict__ Bw,
    void* __restrict__ Cout, const bf16* __restrict__ bias,
    bf16* __restrict__ kb, bf16* __restrict__ vT, int N, int K) {
  __shared__ __align__(16) bf16 As[2][128 * 64];   // 2 x 16 KB
  __shared__ __align__(16) bf16 Bs[2][128 * 64];   // 2 x 16 KB

  const int tid  = threadIdx.x;
  const int w    = tid >> 6;
  const int lane = tid & 63;
  const int quad = lane >> 4;
  const int l16  = lane & 15;
  const int wm   = w & 1;   // row half (64 rows)
  const int wn   = w >> 1;  // col half (64 cols)
  const int m0   = blockIdx.x * 128;
  const int n0   = blockIdx.y * 128;
  const int lrow = lane >> 3;                       // 0..7 (== row&7 staged)
  const int scol = ((lane & 7) ^ lrow) * 8;         // pre-swizzled source col
  const int rx   = (l16 & 7) * 8;                   // read-side XOR term

  f32x4 acc[4][4] = {};

  // 32 gld_lds16 insts: 16 for As (128 rows), 16 for Bs (128 rows); 8/wave
  auto stage = [&](int buf, int k0) {
#pragma unroll
    for (int t = 0; t < 8; ++t) {
      const int inst = w * 8 + t;  // wave-uniform
      if (inst < 16) {
        gld_lds16(&A[(size_t)(m0 + inst * 8 + lrow) * K + k0 + scol],
                  &As[buf][inst * 512]);
      } else {
        const int bi = inst - 16;
        gld_lds16(&Bw[(size_t)(n0 + bi * 8 + lrow) * K + k0 + scol],
                  &Bs[buf][bi * 512]);
      }
    }
  };

  auto compute = [&](int buf) {
#pragma unroll
    for (int kk = 0; kk < 64; kk += 32) {
      const int c = (kk + quad * 8) ^ rx;  // swizzled column (row&7 == l16&7)
      bf16x8 a[4], b[4];
#pragma unroll
      for (int i = 0; i < 4; ++i)
        a[i] = *(const bf16x8*)&As[buf][(wm * 64 + i * 16 + l16) * 64 + c];
#pragma unroll
      for (int j = 0; j < 4; ++j)
        b[j] = *(const bf16x8*)&Bs[buf][(wn * 64 + j * 16 + l16) * 64 + c];
#pragma unroll
      for (int i = 0; i < 4; ++i)
#pragma unroll
        for (int j = 0; j < 4; ++j) acc[i][j] = MFMA(a[i], b[j], acc[i][j]);
    }
  };

  // prologue: fill buf0, sync (vmcnt(0)+barrier inside __syncthreads)
  stage(0, 0);
  __syncthreads();
  int cur = 0;
  for (int k0 = 64; k0 < K; k0 += 64) {
    stage(cur ^ 1, k0);     // issue next-tile loads FIRST (overlap with MFMA)
    compute(cur);
    __syncthreads();        // drains vmcnt: next buf staged; all reads done
    cur ^= 1;
  }
  compute(cur);             // epilogue tile, no prefetch

  // epilogue: C/D layout col=l16, row=quad*4+r (m89-verified)
#pragma unroll
  for (int i = 0; i < 4; ++i) {
#pragma unroll
    for (int j = 0; j < 4; ++j) {
      const int col     = n0 + wn * 64 + j * 16 + l16;
      const int rowbase = m0 + wm * 64 + i * 16 + quad * 4;
      if (EPI == 1) {
        if (col < D_) {
          bf16* qb = (bf16*)Cout;
#pragma unroll
          for (int r = 0; r < 4; ++r)  // fold softmax scale * log2e into q
            qb[(size_t)(rowbase + r) * D_ + col] = (bf16)(acc[i][j][r] * QSCALE);
        } else if (col < D_ + HD_) {
#pragma unroll
          for (int r = 0; r < 4; ++r)
            kb[(size_t)(rowbase + r) * HD_ + (col - D_)] = (bf16)acc[i][j][r];
        } else {
          bf16 o[4] = {(bf16)acc[i][j][0], (bf16)acc[i][j][1],
                       (bf16)acc[i][j][2], (bf16)acc[i][j][3]};
          *(uint2*)&vT[(size_t)(col - D_ - HD_) * M_ + rowbase] = *(const uint2*)o;
        }
      } else {
        float* outp = (float*)Cout;
        const float bvv = (float)bias[col];
#pragma unroll
        for (int r = 0; r < 4; ++r)
          outp[(size_t)(rowbase + r) * D_ + col] = acc[i][j][r] + bvv;
      }
    }
  }
}

// ---------------------------------------------------------------------------
// Windowed attention (MQA), Q-tile = 128, q pre-scaled by QSCALE (exp2
// softmax). QK computed TRANSPOSED (A=K-frag, B=Q-frag -> C/D col=t, row=s).
// Q hoisted to registers; K/V double-buffered + swizzled via global_load_lds.
// R6-verified: NO mid-step barrier (Ps rows are wave-private; same-wave LDS
// write->read ordering via compiler lgkmcnt). One barrier per s-step.
// NEW: fully-masked (tt,stile) groups short-circuit to a zero-fill of Ps
// (wave-uniform bounds check) — skips 4x(fmin+exp2+add+cvt) per group on
// boundary s-steps; attn is VALUBusy=49%-bound (R7 counters).
// Un-normalized softmax (NaN-free); in-place q/o safe.
// ---------------------------------------------------------------------------
__global__ __launch_bounds__(256) void attn_win128(
    const bf16* __restrict__ q, const bf16* __restrict__ k,
    const bf16* __restrict__ vT, bf16* __restrict__ o) {
  __shared__ __align__(16) bf16 Ks[2][64 * 64];   // 16 KB
  __shared__ __align__(16) bf16 Vt[2][64 * 64];   // 16 KB [h][s]
  __shared__ __align__(16) bf16 Ps[128 * 72];     // 18 KB padded (wave-private)
  __shared__ float ls[4][32];                     // per-wave l[t] redistribute

  const int tid  = threadIdx.x;
  const int w    = tid >> 6;
  const int lane = tid & 63;
  const int quad = lane >> 4;
  const int l16  = lane & 15;
  const int lrow = lane >> 3;                     // 0..7 (== row&7 staged)
  const int scol = ((lane & 7) ^ lrow) * 8;       // pre-swizzled source col
  const int rx   = (l16 & 7) * 8;                 // read-side XOR term

  const int t0 = blockIdx.x * 128;
  const int n  = blockIdx.y;
  const int b  = blockIdx.z;

  auto stageKV = [&](int st, int pb) {
#pragma unroll
    for (int t = 0; t < 2; ++t) {
      const int inst = w * 2 + t;
      gld_lds16(&k[((size_t)(b * T_ + st + inst * 8 + lrow)) * HD_ + scol],
                &Ks[pb][inst * 512]);
      gld_lds16(&vT[(size_t)(inst * 8 + lrow) * M_ + b * T_ + st + scol],
                &Vt[pb][inst * 512]);
    }
  };

  const int st_lo = (t0 - WIN_ > 0) ? t0 - WIN_ : 0;
  const int st_hi = (t0 + WIN_ + 64 < T_ - 64) ? t0 + WIN_ + 64 : T_ - 64;

  stageKV(st_lo, 0);
  int pb = 0;

  // Q-hoist: wave's B-fragments for both kk slices, direct from global.
  bf16x8 qf[2][2];
#pragma unroll
  for (int tt = 0; tt < 2; ++tt)
#pragma unroll
    for (int kq = 0; kq < 2; ++kq)
      qf[tt][kq] = *(const bf16x8*)
          &q[((size_t)(b * T_ + t0 + w * 32 + tt * 16 + l16)) * D_ +
             n * HD_ + kq * 32 + quad * 8];

  f32x4 o_acc[2][4] = {};
  float l_part[2] = {0.0f, 0.0f};  // per-t partials, t = t0 + w*32 + tt*16 + l16

  for (int st = st_lo; st <= st_hi; st += 64) {
    __syncthreads();  // drains vmcnt: buf[pb] ready; prior PV reads done
    if (st + 64 <= st_hi) stageKV(st + 64, pb ^ 1);  // overlapped prefetch

    // S^T = K Q^T : MFMA(A=K-frag, B=Q-frag) -> C/D col=t, row=s
    f32x4 sacc[4][2] = {};  // [stile][tt]
#pragma unroll
    for (int kk = 0; kk < 64; kk += 32) {
      const int c = (kk + quad * 8) ^ rx;  // swizzled col (K rows: row&7==l16&7)
      bf16x8 ak[4];
#pragma unroll
      for (int stile = 0; stile < 4; ++stile)
        ak[stile] = *(const bf16x8*)&Ks[pb][(stile * 16 + l16) * 64 + c];
      __builtin_amdgcn_s_setprio(1);
#pragma unroll
      for (int stile = 0; stile < 4; ++stile)
#pragma unroll
        for (int tt = 0; tt < 2; ++tt)
          sacc[stile][tt] = MFMA(ak[stile], qf[tt][kk >> 5], sacc[stile][tt]);
      __builtin_amdgcn_s_setprio(0);
    }

    // softmax numerators (exp2); lane holds col t = w*32+tt*16+l16,
    // rows s = stile*16+quad*4+r -> b64 stores into Ps (wave-private rows)
    const int off_t = st - t0;
    const bool need_mask =
        (off_t < w * 32 - (WIN_ - 31)) || (off_t > w * 32 + (WIN_ - 63));
    if (!need_mask) {
#pragma unroll
      for (int tt = 0; tt < 2; ++tt) {
#pragma unroll
        for (int stile = 0; stile < 4; ++stile) {
          bf16 pk[4];
          float psum = 0.0f;
#pragma unroll
          for (int r = 0; r < 4; ++r) {
            const float p =
                __builtin_amdgcn_exp2f(fminf(sacc[stile][tt][r], 43.28f));
            psum += p;
            pk[r] = (bf16)p;
          }
          l_part[tt] += psum;
          *(uint2*)&Ps[(w * 32 + tt * 16 + l16) * 72 + stile * 16 + quad * 4] =
              *(const uint2*)pk;
        }
      }
    } else {
#pragma unroll
      for (int tt = 0; tt < 2; ++tt) {
        const int t   = t0 + w * 32 + tt * 16 + l16;
        const int tlo = t0 + w * 32 + tt * 16;      // wave-uniform t range
#pragma unroll
        for (int stile = 0; stile < 4; ++stile) {
          const int slo = st + stile * 16;          // wave-uniform s range
          // fully-masked 16x16 group: min|t-s| over the tile > WIN_
          if (slo - (tlo + 15) > WIN_ || tlo - (slo + 15) > WIN_) {
            const uint2 z = {0u, 0u};               // zero-fill Ps, skip VALU
            *(uint2*)&Ps[(w * 32 + tt * 16 + l16) * 72 + stile * 16 + quad * 4] = z;
          } else {
            bf16 pk[4];
            float psum = 0.0f;
#pragma unroll
            for (int r = 0; r < 4; ++r) {
              const int s = slo + quad * 4 + r;
              const int d = t - s;
              const float p =
                  (d > WIN_ || d < -WIN_)
                      ? 0.0f
                      : __builtin_amdgcn_exp2f(fminf(sacc[stile][tt][r], 43.28f));
              psum += p;
              pk[r] = (bf16)p;
            }
            l_part[tt] += psum;
            *(uint2*)&Ps[(w * 32 + tt * 16 + l16) * 72 + stile * 16 + quad * 4] =
                *(const uint2*)pk;
          }
        }
      }
    }
    // NO barrier here: Ps rows are wave-private; lgkmcnt orders write->read.

    // O += P V  (A-frag: Ps rows t contiguous in s; B-frag: Vt rows h)
#pragma unroll
    for (int kk = 0; kk < 64; kk += 32) {
      const int c = (kk + quad * 8) ^ rx;  // swizzled col for Vt
      bf16x8 ap[2];
#pragma unroll
      for (int rg = 0; rg < 2; ++rg)
        ap[rg] = *(const bf16x8*)&Ps[(w * 32 + rg * 16 + l16) * 72 + kk + quad * 8];
      __builtin_amdgcn_s_setprio(1);
#pragma unroll
      for (int nt = 0; nt < 4; ++nt) {
        bf16x8 bv = *(const bf16x8*)&Vt[pb][(nt * 16 + l16) * 64 + c];
#pragma unroll
        for (int rg = 0; rg < 2; ++rg)
          o_acc[rg][nt] = MFMA(ap[rg], bv, o_acc[rg][nt]);
      }
      __builtin_amdgcn_s_setprio(0);
    }
    pb ^= 1;
  }

  // finalize l[t]: reduce per-t partials across the 4 quads, redistribute
#pragma unroll
  for (int tt = 0; tt < 2; ++tt) {
    l_part[tt] += __shfl_xor(l_part[tt], 16);
    l_part[tt] += __shfl_xor(l_part[tt], 32);
    if (quad == 0) ls[w][tt * 16 + l16] = l_part[tt];
  }
  __syncthreads();

#pragma unroll
  for (int rg = 0; rg < 2; ++rg) {
#pragma unroll
    for (int r = 0; r < 4; ++r) {
      const float lr = ls[w][rg * 16 + quad * 4 + r] + 1e-30f;
      const int t = t0 + w * 32 + rg * 16 + quad * 4 + r;
#pragma unroll
      for (int nt = 0; nt < 4; ++nt) {
        const int h = nt * 16 + l16;
        o[((size_t)(b * T_ + t)) * D_ + n * HD_ + h] =
            (bf16)(o_acc[rg][nt][r] / lr);
      }
    }
  }
}

// ---------------------------------------------------------------------------
extern "C" void kernel_launch(void* const* d_in, const int* in_sizes, int n_in,
                              void* d_out, int out_size, void* d_ws, size_t ws_size,
                              hipStream_t stream) {
  float* out = (float*)d_out;  // reference output dtype is float32

  bf16* xc   = (bf16*)d_ws;                   // 4096 x 1024
  bf16* wqkv = xc   + (size_t)M_ * D_;        // 1152 x 1024
  bf16* wfc  = wqkv + (size_t)NQKV * D_;      // 1024 x 1024
  bf16* bfc  = wfc  + (size_t)D_ * D_;        // 1024
  bf16* qb   = bfc  + D_;                     // 4096 x 1024 (attn out in-place)
  bf16* kb   = qb   + (size_t)M_ * D_;        // 4096 x 64
  bf16* vT   = kb   + (size_t)M_ * HD_;       // 64 x 4096 (transposed)

  dim3 blk(256);
  conv_all<<<dim3((6423552 / 4 + 255) / 256), blk, 0, stream>>>(
      (const float*)d_in[0], (const float*)d_in[1], (const float*)d_in[2],
      (const float*)d_in[3], (const float*)d_in[4], (const float*)d_in[5],
      xc, wqkv, wfc, bfc);

  gemm128x128<1><<<dim3(M_ / 128, NQKV / 128), blk, 0, stream>>>(
      xc, wqkv, (void*)qb, nullptr, kb, vT, NQKV, D_);

  attn_win128<<<dim3(T_ / 128, NH_, B_), blk, 0, stream>>>(qb, kb, vT, qb);

  gemm128x128<2><<<dim3(M_ / 128, D_ / 128), blk, 0, stream>>>(
      qb, wfc, (void*)out, bfc, nullptr, nullptr, D_, D_);
}